// Round 3
// baseline (343.646 us; speedup 1.0000x reference)
//
#include <hip/hip_runtime.h>

typedef _Float16 half8 __attribute__((ext_vector_type(8)));
typedef float float4v __attribute__((ext_vector_type(4)));
typedef int int4v __attribute__((ext_vector_type(4)));

#define KSIG (-1.442695041f)
#define KTANH (-2.885390082f)

__device__ __forceinline__ float fexp2(float x) { return __builtin_amdgcn_exp2f(x); }
__device__ __forceinline__ float frcp(float x) { return __builtin_amdgcn_rcpf(x); }

union H8 {
  half8 v;
  _Float16 a[8];
};

// Per-cell weights as MFMA B-fragments (hi/lo f16 split), kexp folded in.
// B-frag layout (16x16x32): lane holds B[n=lane&15][k=(lane>>4)*8+j], j=0..7.
// n = gate row (PyTorch order: 0..4=i, 5..9=f, 10..14=g, 15..19=o).
// k = input dim: 0..4 = x (Wih), 5..9 = h (Whh), 10..31 = zero pad.
struct CellW {
  half8 bh[2], bl[2];  // [N-tile]: tile0 = gates 0..15, tile1 = gates 16..19
  float4v bias[2];     // C-init = kexp*(bih+bhh), broadcast over 4 rows
};

__device__ __forceinline__ void load_cellW(CellW& cw, int lane,
                                           const float* __restrict__ Wih,
                                           const float* __restrict__ Whh,
                                           const float* __restrict__ bih,
                                           const float* __restrict__ bhh) {
  int n0 = lane & 15, q = lane >> 4;
#pragma unroll
  for (int tl = 0; tl < 2; ++tl) {
    int n = tl * 16 + n0;
    float kx = (n >= 10 && n < 15) ? KTANH : KSIG;
    float bv = (n < 20) ? kx * (bih[n] + bhh[n]) : 0.f;
    cw.bias[tl] = (float4v){bv, bv, bv, bv};
    H8 hh, hl;
#pragma unroll
    for (int j = 0; j < 8; ++j) {
      int k = q * 8 + j;
      float w = 0.f;
      if (n < 20 && k < 10) w = kx * (k < 5 ? Wih[n * 5 + k] : Whh[n * 5 + (k - 5)]);
      _Float16 wh = (_Float16)w;
      hh.a[j] = wh;
      hl.a[j] = (_Float16)(w - (float)wh);
    }
    cw.bh[tl] = hh.v;
    cw.bl[tl] = hl.v;
  }
}

// Write one fp32 value into the A-image as f16 hi (at byteoff) + f16 lo (+1024).
__device__ __forceinline__ void wr_hl(char* base, int byteoff, float v) {
  _Float16 h = (_Float16)v;
  *(_Float16*)(base + byteoff) = h;
  *(_Float16*)(base + 1024 + byteoff) = (_Float16)(v - (float)h);
}

// Per-cell LDS region: [0,1024) A-image hi, [1024,2048) A-image lo,
// [2048, 2048+16*33*4) gate buffer sG (padded stride 33 words).
#define CELL_LDS 4160

// One cell timestep for 16 elements (one wave).
// Inputs for this step must already be in the A-image x-slots (k=0..4);
// h-slots (k=5..9) hold h(t-1) from the previous call (or 0).
__device__ __forceinline__ void cell_iter(
    char* base, const CellW& cw, int l, int q, int n0, float m2_0, float a2_0,
    int gr0, int gr1, int hw0, int hw1, bool p1v, float* cst, float* hout,
    char* fwd_base, int aw0, int aw1) {
  half8 ah = *(const half8*)(base + l * 16);
  half8 al = *(const half8*)(base + 1024 + l * 16);

  float4v acc0 = __builtin_amdgcn_mfma_f32_16x16x32_f16(ah, cw.bh[0], cw.bias[0], 0, 0, 0);
  acc0 = __builtin_amdgcn_mfma_f32_16x16x32_f16(al, cw.bh[0], acc0, 0, 0, 0);
  acc0 = __builtin_amdgcn_mfma_f32_16x16x32_f16(ah, cw.bl[0], acc0, 0, 0, 0);
  float4v acc1 = __builtin_amdgcn_mfma_f32_16x16x32_f16(ah, cw.bh[1], cw.bias[1], 0, 0, 0);
  acc1 = __builtin_amdgcn_mfma_f32_16x16x32_f16(al, cw.bh[1], acc1, 0, 0, 0);
  acc1 = __builtin_amdgcn_mfma_f32_16x16x32_f16(ah, cw.bl[1], acc1, 0, 0, 0);

  // Activations in C/D layout: col=lane&15 (gate n), row=(lane>>4)*4+r (elem).
  float* sG = (float*)(base + 2048);
#pragma unroll
  for (int r = 0; r < 4; ++r) {
    int row = q * 4 + r;
    float g0 = fmaf(m2_0, frcp(1.f + fexp2(acc0[r])), a2_0);
    sG[row * 33 + n0] = g0;
    float g1 = frcp(1.f + fexp2(acc1[r]));  // gates 16..19 are o-gates (sigmoid)
    sG[row * 33 + 16 + n0] = g1;
  }

  // State update: 80 (e,j) pairs over 64 lanes (lanes>=16 duplicate pair1).
#pragma unroll
  for (int p = 0; p < 2; ++p) {
    int gr = p ? gr1 : gr0;
    float I = sG[gr], F = sG[gr + 5], G = sG[gr + 10], O = sG[gr + 15];
    float c = fmaf(F, cst[p], I * G);
    cst[p] = c;
    float th = fmaf(2.f, frcp(1.f + fexp2(KTANH * c)), -1.f);
    float h = O * th;
    hout[p] = h;
    bool w = p ? p1v : true;
    if (w) {
      wr_hl(base, p ? hw1 : hw0, h);                 // own h-slot (k=5+j)
      if (fwd_base) wr_hl(fwd_base, p ? aw1 : aw0, h);  // next cell's x-slot (k=j)
    }
  }
}

__global__ __launch_bounds__(64) void rnn_mfma_kernel(
    const float* __restrict__ x1, const float* __restrict__ x2,
    const float* __restrict__ Wih1, const float* __restrict__ Whh1,
    const float* __restrict__ bih1, const float* __restrict__ bhh1,
    const float* __restrict__ Wih2a, const float* __restrict__ Whh2a,
    const float* __restrict__ bih2a, const float* __restrict__ bhh2a,
    const float* __restrict__ Wih2b, const float* __restrict__ Whh2b,
    const float* __restrict__ bih2b, const float* __restrict__ bhh2b,
    float* __restrict__ wsh1, float* __restrict__ wsh2, int B) {
  __shared__ __align__(16) unsigned char sMem[3 * CELL_LDS];
  char* base0 = (char*)sMem;                // lstm1
  char* base1 = (char*)sMem + CELL_LDS;     // lstm2a
  char* base2 = (char*)sMem + 2 * CELL_LDS; // lstm2b

  const int l = threadIdx.x;
  const int g = blockIdx.x;
  const int n0 = l & 15, q = l >> 4;

  CellW w0, w1, w2;
  load_cellW(w0, l, Wih1, Whh1, bih1, bhh1);
  load_cellW(w1, l, Wih2a, Whh2a, bih2a, bhh2a);
  load_cellW(w2, l, Wih2b, Whh2b, bih2b, bhh2b);

  // Zero all A-images once (covers h(-1)=0 and the k>=10 / lanes>=32 padding;
  // garbage there would make 0*NaN = NaN inside the MFMA).
  int4v z = (int4v){0, 0, 0, 0};
  *(int4v*)(base0 + l * 16) = z;
  *(int4v*)(base0 + 1024 + l * 16) = z;
  *(int4v*)(base1 + l * 16) = z;
  *(int4v*)(base1 + 1024 + l * 16) = z;
  *(int4v*)(base2 + l * 16) = z;
  *(int4v*)(base2 + 1024 + l * 16) = z;

  // tile0 act consts (g-gates n=10..14 are tanh; others sigmoid)
  const float m2_0 = (n0 >= 10 && n0 < 15) ? 2.f : 1.f;
  const float a2_0 = (n0 >= 10 && n0 < 15) ? -1.f : 0.f;

  // pair/slot mapping: slot s -> (e=s/5, j=s%5); pair0 s=l, pair1 s=64+(l&15)
  const int e0 = (l * 205) >> 10, j0 = l - e0 * 5;
  const int s1i = 64 + n0;
  const int e1 = (s1i * 205) >> 10, j1 = s1i - e1 * 5;
  const bool p1v = (l < 16);

  // x global pointers per slot
  const float* px1_0 = x1 + (size_t)(g * 16 + e0) * 640 + j0;
  const float* px1_1 = x1 + (size_t)(g * 16 + e1) * 640 + j1;
  const float* px2_0 = x2 + (size_t)(g * 16 + e0) * 640 + j0;
  const float* px2_1 = x2 + (size_t)(g * 16 + e1) * 640 + j1;

  // A-image byte addrs: x-slot (k=j) and h-slot (k=5+j)
  const int xw0 = e0 * 16 + j0 * 2;
  const int xw1 = e1 * 16 + j1 * 2;
  const int k0 = 5 + j0;
  const int hw0 = (k0 < 8) ? (e0 * 16 + k0 * 2) : ((16 + e0) * 16 + (k0 - 8) * 2);
  const int k1 = 5 + j1;
  const int hw1 = (k1 < 8) ? (e1 * 16 + k1 * 2) : ((16 + e1) * 16 + (k1 - 8) * 2);

  // sG read bases (word index)
  const int gr0 = e0 * 33 + j0;
  const int gr1 = e1 * 33 + j1;

  float c0[2] = {0.f, 0.f}, c1s[2] = {0.f, 0.f}, c2[2] = {0.f, 0.f};
  float h1o[2] = {0.f, 0.f}, h2ao[2] = {0.f, 0.f}, h2bo[2] = {0.f, 0.f};

  float xa0 = px1_0[0], xa1 = px1_1[0];
  float xb0 = px2_0[0], xb1 = px2_1[0];

  for (int t = 0; t < 128; ++t) {
    // stage x(t) into images of c1 / c2a
    wr_hl(base0, xw0, xa0);
    if (p1v) wr_hl(base0, xw1, xa1);
    wr_hl(base1, xw0, xb0);
    if (p1v) wr_hl(base1, xw1, xb1);

    // prefetch x(t+1)
    int tn = (t < 127) ? t + 1 : 127;
    xa0 = px1_0[tn * 5];
    xa1 = px1_1[tn * 5];
    xb0 = px2_0[tn * 5];
    xb1 = px2_1[tn * 5];

    cell_iter(base0, w0, l, q, n0, m2_0, a2_0, gr0, gr1, hw0, hw1, p1v, c0,
              h1o, nullptr, 0, 0);
    cell_iter(base1, w1, l, q, n0, m2_0, a2_0, gr0, gr1, hw0, hw1, p1v, c1s,
              h2ao, base2, xw0, xw1);  // h2a(t) -> c2b x-slots
    cell_iter(base2, w2, l, q, n0, m2_0, a2_0, gr0, gr1, hw0, hw1, p1v, c2,
              h2bo, nullptr, 0, 0);
  }

  // out1 = h1(127), out2 = h2b(127): fp32, slot s -> element g*16+e, comp j
  wsh1[(size_t)g * 80 + l] = h1o[0];
  wsh2[(size_t)g * 80 + l] = h2bo[0];
  if (p1v) {
    wsh1[(size_t)g * 80 + 64 + l] = h1o[1];
    wsh2[(size_t)g * 80 + 64 + l] = h2bo[1];
  }
}

__global__ __launch_bounds__(64) void fc_kernel(
    const float* __restrict__ x1, const float* __restrict__ x2,
    const float* __restrict__ wsh1, const float* __restrict__ wsh2,
    const float* __restrict__ W1, const float* __restrict__ b1,
    const float* __restrict__ W2, const float* __restrict__ b2,
    const float* __restrict__ W3, const float* __restrict__ b3,
    const float* __restrict__ W4, const float* __restrict__ b4,
    const float* __restrict__ W5, const float* __restrict__ b5,
    float* __restrict__ out, int B) {
  int e = blockIdx.x * 64 + threadIdx.x;
  if (e >= B) return;
  float in0[20];
#pragma unroll
  for (int k = 0; k < 5; ++k) {
    in0[k] = x1[(size_t)e * 640 + 635 + k];
    in0[5 + k] = x2[(size_t)e * 640 + 635 + k];
    in0[10 + k] = wsh1[(size_t)e * 5 + k];
    in0[15 + k] = wsh2[(size_t)e * 5 + k];
  }
  float v1[32];
#pragma unroll
  for (int n = 0; n < 32; ++n) {
    float acc = b1[n];
#pragma unroll
    for (int k = 0; k < 20; ++k) acc = fmaf(W1[n * 20 + k], in0[k], acc);
    v1[n] = fmaxf(acc, 0.f);
  }
  float v2[32];
#pragma unroll
  for (int n = 0; n < 32; ++n) {
    float acc = b2[n];
#pragma unroll
    for (int k = 0; k < 32; ++k) acc = fmaf(W2[n * 32 + k], v1[k], acc);
    v2[n] = fmaxf(acc, 0.f);
  }
  float v3[16];
#pragma unroll
  for (int n = 0; n < 16; ++n) {
    float acc = b3[n];
#pragma unroll
    for (int k = 0; k < 32; ++k) acc = fmaf(W3[n * 32 + k], v2[k], acc);
    v3[n] = fmaxf(acc, 0.f);
  }
  float v4[16];
#pragma unroll
  for (int n = 0; n < 16; ++n) {
    float acc = b4[n];
#pragma unroll
    for (int k = 0; k < 16; ++k) acc = fmaf(W4[n * 16 + k], v3[k], acc);
    v4[n] = fmaxf(acc, 0.f);
  }
#pragma unroll
  for (int n = 0; n < 5; ++n) {
    float acc = b5[n];
#pragma unroll
    for (int k = 0; k < 16; ++k) acc = fmaf(W5[n * 16 + k], v4[k], acc);
    out[(size_t)e * 5 + n] = acc;
  }
}

extern "C" void kernel_launch(void* const* d_in, const int* in_sizes, int n_in,
                              void* d_out, int out_size, void* d_ws,
                              size_t ws_size, hipStream_t stream) {
  const float* x1 = (const float*)d_in[0];
  const float* x2 = (const float*)d_in[1];
  const float* Wih1 = (const float*)d_in[2];
  const float* Whh1 = (const float*)d_in[3];
  const float* bih1 = (const float*)d_in[4];
  const float* bhh1 = (const float*)d_in[5];
  const float* Wih2a = (const float*)d_in[6];
  const float* Whh2a = (const float*)d_in[7];
  const float* bih2a = (const float*)d_in[8];
  const float* bhh2a = (const float*)d_in[9];
  const float* Wih2b = (const float*)d_in[10];
  const float* Whh2b = (const float*)d_in[11];
  const float* bih2b = (const float*)d_in[12];
  const float* bhh2b = (const float*)d_in[13];
  const float* W1 = (const float*)d_in[14];
  const float* b1 = (const float*)d_in[15];
  const float* W2 = (const float*)d_in[16];
  const float* b2 = (const float*)d_in[17];
  const float* W3 = (const float*)d_in[18];
  const float* b3 = (const float*)d_in[19];
  const float* W4 = (const float*)d_in[20];
  const float* b4 = (const float*)d_in[21];
  const float* W5 = (const float*)d_in[22];
  const float* b5 = (const float*)d_in[23];

  int B = in_sizes[0] / 640;  // [B,128,5]
  // h1 staged in d_out (overwritten by fc_kernel afterwards), h2b in d_ws.
  float* wsh1 = (float*)d_out;
  float* wsh2 = (float*)d_ws;

  rnn_mfma_kernel<<<B / 16, 64, 0, stream>>>(x1, x2, Wih1, Whh1, bih1, bhh1,
                                             Wih2a, Whh2a, bih2a, bhh2a, Wih2b,
                                             Whh2b, bih2b, bhh2b, wsh1, wsh2, B);
  fc_kernel<<<(B + 63) / 64, 64, 0, stream>>>(x1, x2, wsh1, wsh2, W1, b1, W2,
                                              b2, W3, b3, W4, b4, W5, b5,
                                              (float*)d_out, B);
}

// Round 4
// 241.949 us; speedup vs baseline: 1.4203x; 1.4203x over previous
//
#include <hip/hip_runtime.h>

#define DEV __device__ __forceinline__
#define KSIG (-1.442695041f)
#define KTANH (-2.885390082f)

DEV float fexp2(float x) { return __builtin_amdgcn_exp2f(x); }
DEV float frcp(float x) { return __builtin_amdgcn_rcpf(x); }
DEV float bperm(int a, float x) {
  return __int_as_float(__builtin_amdgcn_ds_bpermute(a, __float_as_int(x)));
}

// Lane u of a 5-lane group owns state index j=u and the 4 gate rows
// {u, 5+u, 10+u, 15+u} (i,f,g,o). kexp is folded into weights/bias:
// sigmoid rows scaled by KSIG, tanh (g) row by KTANH, so activation is just
// r = rcp(1+exp2(acc)); sigma = r; tanh = 2r-1.
struct CellB {
  float w[4][10];  // [row-type][k]: k<5 = Wih, k>=5 = Whh
  float b[4];
};

DEV void load_cellB(CellB& W, int u, const float* __restrict__ Wih,
                    const float* __restrict__ Whh,
                    const float* __restrict__ bih,
                    const float* __restrict__ bhh) {
#pragma unroll
  for (int rt = 0; rt < 4; ++rt) {  // 0=i 1=f 2=g 3=o
    int row = 5 * rt + u;
    float kx = (rt == 2) ? KTANH : KSIG;
#pragma unroll
    for (int k = 0; k < 5; ++k) {
      W.w[rt][k] = kx * Wih[row * 5 + k];
      W.w[rt][5 + k] = kx * Whh[row * 5 + k];
    }
    W.b[rt] = kx * (bih[row] + bhh[row]);
  }
}

// One cell timestep. hAll holds h(t-1)[0..4] on entry, h(t)[0..4] on exit
// (shared across the 5-lane group via ds_bpermute). c is this lane's c_j.
DEV void cellB_step(const CellB& W, const float xin[5], float hAll[5],
                    float& c, const int bp[5]) {
  float acc[4];
#pragma unroll
  for (int rt = 0; rt < 4; ++rt) {
    float a = W.b[rt];
#pragma unroll
    for (int k = 0; k < 5; ++k) a = fmaf(W.w[rt][k], xin[k], a);
#pragma unroll
    for (int k = 0; k < 5; ++k) a = fmaf(W.w[rt][5 + k], hAll[k], a);
    acc[rt] = a;
  }
  float gi = frcp(1.f + fexp2(acc[0]));
  float gf = frcp(1.f + fexp2(acc[1]));
  float gg = fmaf(2.f, frcp(1.f + fexp2(acc[2])), -1.f);
  float go = frcp(1.f + fexp2(acc[3]));
  c = fmaf(gf, c, gi * gg);
  float th = fmaf(2.f, frcp(1.f + fexp2(KTANH * c)), -1.f);
  float h = go * th;  // this lane's h_j(t)
#pragma unroll
  for (int u2 = 0; u2 < 5; ++u2) hAll[u2] = bperm(bp[u2], h);
}

// One wave per block; 12 five-lane groups (lanes 60..63 idle for the RNN).
// Each group = one batch element; all 3 cells serial in-thread (cell1 is
// independent of the 2a->2b chain, providing ILP to cover bpermute latency).
__global__ __launch_bounds__(64, 2) void rnn5_kernel(
    const float* __restrict__ x1, const float* __restrict__ x2,
    const float* __restrict__ Wih1, const float* __restrict__ Whh1,
    const float* __restrict__ bih1, const float* __restrict__ bhh1,
    const float* __restrict__ Wih2a, const float* __restrict__ Whh2a,
    const float* __restrict__ bih2a, const float* __restrict__ bhh2a,
    const float* __restrict__ Wih2b, const float* __restrict__ Whh2b,
    const float* __restrict__ bih2b, const float* __restrict__ bhh2b,
    const float* __restrict__ W1, const float* __restrict__ b1,
    const float* __restrict__ W2, const float* __restrict__ b2,
    const float* __restrict__ W3, const float* __restrict__ b3,
    const float* __restrict__ W4, const float* __restrict__ b4,
    const float* __restrict__ W5, const float* __restrict__ b5,
    float* __restrict__ out, int B) {
  __shared__ float sIn[12][20];
  __shared__ float sA[12][32];
  __shared__ float sB[12][32];

  const int l = threadIdx.x;
  const int g = l / 5;
  const int u = l - 5 * g;
  const bool act = (g < 12);
  const int el = act ? g : 11;
  const int eg = blockIdx.x * 12 + el;
  const int egc = (eg < B) ? eg : (B - 1);

  CellB Wc0, Wc1, Wc2;
  load_cellB(Wc0, u, Wih1, Whh1, bih1, bhh1);
  load_cellB(Wc1, u, Wih2a, Whh2a, bih2a, bhh2a);
  load_cellB(Wc2, u, Wih2b, Whh2b, bih2b, bhh2b);

  int bp[5];
#pragma unroll
  for (int u2 = 0; u2 < 5; ++u2) bp[u2] = (5 * g + u2) * 4;

  const float* px1 = x1 + (size_t)egc * 640;
  const float* px2 = x2 + (size_t)egc * 640;

  float h1[5], h2a[5], h2b[5];
  float c1 = 0.f, c2 = 0.f, c3 = 0.f;
  float xa[5], xb[5];
#pragma unroll
  for (int k = 0; k < 5; ++k) {
    h1[k] = h2a[k] = h2b[k] = 0.f;
    xa[k] = px1[k];
    xb[k] = px2[k];
  }

  for (int t = 0; t < 128; ++t) {
    const int tn = (t < 127) ? t + 1 : 127;
    float na[5], nb[5];
#pragma unroll
    for (int k = 0; k < 5; ++k) {  // prefetch x(t+1)
      na[k] = px1[tn * 5 + k];
      nb[k] = px2[tn * 5 + k];
    }
    cellB_step(Wc0, xa, h1, c1, bp);
    cellB_step(Wc1, xb, h2a, c2, bp);
    cellB_step(Wc2, h2a, h2b, c3, bp);  // consumes h2a(t) same iteration
#pragma unroll
    for (int k = 0; k < 5; ++k) {
      xa[k] = na[k];
      xb[k] = nb[k];
    }
  }

  // Stage FC inputs: [x1_last, x2_last, h1, h2b]; lane u writes component u.
  if (act) {
    sIn[el][u] = xa[u];
    sIn[el][5 + u] = xb[u];
    sIn[el][10 + u] = h1[u];
    sIn[el][15 + u] = h2b[u];
  }
  __syncthreads();

  // FC stack: task-split over the wave; weights from global (L1/L2 cached).
  for (int task = l; task < 12 * 32; task += 64) {
    int e = task >> 5, n = task & 31;
    float acc = b1[n];
#pragma unroll
    for (int k = 0; k < 20; ++k) acc = fmaf(W1[n * 20 + k], sIn[e][k], acc);
    sA[e][n] = fmaxf(acc, 0.f);
  }
  __syncthreads();
  for (int task = l; task < 12 * 32; task += 64) {
    int e = task >> 5, n = task & 31;
    float acc = b2[n];
#pragma unroll
    for (int k = 0; k < 32; ++k) acc = fmaf(W2[n * 32 + k], sA[e][k], acc);
    sB[e][n] = fmaxf(acc, 0.f);
  }
  __syncthreads();
  for (int task = l; task < 12 * 16; task += 64) {
    int e = task >> 4, n = task & 15;
    float acc = b3[n];
#pragma unroll
    for (int k = 0; k < 32; ++k) acc = fmaf(W3[n * 32 + k], sB[e][k], acc);
    sA[e][n] = fmaxf(acc, 0.f);  // reuse sA cols 0..15
  }
  __syncthreads();
  for (int task = l; task < 12 * 16; task += 64) {
    int e = task >> 4, n = task & 15;
    float acc = b4[n];
#pragma unroll
    for (int k = 0; k < 16; ++k) acc = fmaf(W4[n * 16 + k], sA[e][k], acc);
    sB[e][n] = fmaxf(acc, 0.f);
  }
  __syncthreads();
  if (l < 60) {  // 12 elems x 5 outputs
    int e = l / 5, n = l - 5 * (l / 5);
    float acc = b5[n];
#pragma unroll
    for (int k = 0; k < 16; ++k) acc = fmaf(W5[n * 16 + k], sB[e][k], acc);
    int ego = blockIdx.x * 12 + e;
    if (ego < B) out[(size_t)ego * 5 + n] = acc;
  }
}

extern "C" void kernel_launch(void* const* d_in, const int* in_sizes, int n_in,
                              void* d_out, int out_size, void* d_ws,
                              size_t ws_size, hipStream_t stream) {
  const float* x1 = (const float*)d_in[0];
  const float* x2 = (const float*)d_in[1];
  const float* Wih1 = (const float*)d_in[2];
  const float* Whh1 = (const float*)d_in[3];
  const float* bih1 = (const float*)d_in[4];
  const float* bhh1 = (const float*)d_in[5];
  const float* Wih2a = (const float*)d_in[6];
  const float* Whh2a = (const float*)d_in[7];
  const float* bih2a = (const float*)d_in[8];
  const float* bhh2a = (const float*)d_in[9];
  const float* Wih2b = (const float*)d_in[10];
  const float* Whh2b = (const float*)d_in[11];
  const float* bih2b = (const float*)d_in[12];
  const float* bhh2b = (const float*)d_in[13];
  const float* W1 = (const float*)d_in[14];
  const float* b1 = (const float*)d_in[15];
  const float* W2 = (const float*)d_in[16];
  const float* b2 = (const float*)d_in[17];
  const float* W3 = (const float*)d_in[18];
  const float* b3 = (const float*)d_in[19];
  const float* W4 = (const float*)d_in[20];
  const float* b4 = (const float*)d_in[21];
  const float* W5 = (const float*)d_in[22];
  const float* b5 = (const float*)d_in[23];

  int B = in_sizes[0] / 640;       // [B,128,5]
  int blocks = (B + 11) / 12;      // 12 elements per 64-thread block

  rnn5_kernel<<<blocks, 64, 0, stream>>>(
      x1, x2, Wih1, Whh1, bih1, bhh1, Wih2a, Whh2a, bih2a, bhh2a, Wih2b, Whh2b,
      bih2b, bhh2b, W1, b1, W2, b2, W3, b3, W4, b4, W5, b5, (float*)d_out, B);
}